// Round 9
// baseline (3753.431 us; speedup 1.0000x reference)
//
#include <hip/hip_runtime.h>
#include <cstdint>
#include <cstddef>

#define T_LEN   4096
#define B_SZ    32
#define H_DIM   128
#define DX      128
#define K_CLS   10
#define CHUNK   32
#define NCHUNKS (T_LEN / CHUNK)
#define XA_LD   136   // f16 per xA row
#define XP_LD   520   // f16 per xPL row: 128 units * 4 (r,z,n,pad) + 8 pad
#define HI_LD   136

typedef _Float16 half2v  __attribute__((ext_vector_type(2)));
typedef _Float16 half4   __attribute__((ext_vector_type(4)));
typedef _Float16 half8   __attribute__((ext_vector_type(8)));
typedef float    floatx4 __attribute__((ext_vector_type(4)));

// Raw barrier: orders LDS ops only (no vmcnt drain).
#define LGKM_BARRIER() do {                                   \
    asm volatile("s_waitcnt lgkmcnt(0)" ::: "memory");        \
    __builtin_amdgcn_s_barrier();                             \
    asm volatile("" ::: "memory");                            \
  } while (0)

__global__ void __launch_bounds__(256) init_out_kernel(float* __restrict__ out,
                                                       const float* __restrict__ bfc) {
  int i = blockIdx.x * 256 + threadIdx.x;
  if (i < B_SZ * T_LEN * K_CLS) out[i] = bfc[i % K_CLS];
}

// One block per batch element, BOTH directions fused in 512 threads (8 waves).
// Wave w: grp = w>>2 (direction), lwv = w&3 (32-unit slice). HW assigns wave w
// to SIMD w%4, so EVERY SIMD hosts one forward-scan wave + one backward-scan
// wave — two INDEPENDENT scans interleaving: one wave's ds-latency/gate-chain
// windows are filled by the other's MFMA issue. Shared barrier retires one
// step of both scans per round (fixed round costs amortized 2x).
//
// REGISTER BUDGET: the HIP __launch_bounds__ 2nd arg empirically acts as
// CUDA min-BLOCKS/CU on this toolchain: (256,1)->cap512, (512,2)->cap128
// (spilled the 192 stationary weight VGPRs, R8 = 3.7ms), (1024,*)->cap64.
// So pin the backend directly: amdgpu_waves_per_eu(2,2) -> exactly 2
// waves/SIMD -> VGPR cap 256; this body needs ~240.
__global__ void __launch_bounds__(512) __attribute__((amdgpu_waves_per_eu(2, 2)))
gru_bidir_kernel(const float* __restrict__ x,
                 const float* __restrict__ Wih_f, const float* __restrict__ Whh_f,
                 const float* __restrict__ bih_f, const float* __restrict__ bhh_f,
                 const float* __restrict__ Wih_b, const float* __restrict__ Whh_b,
                 const float* __restrict__ bih_b, const float* __restrict__ bhh_b,
                 const float* __restrict__ Wfc, float* __restrict__ out) {
  const int tid  = threadIdx.x;
  const int b    = blockIdx.x;      // 0..31
  const int grp  = tid >> 8;        // 0/1 = direction (wave>>2)
  const int ltid = tid & 255;       // thread id within group
  const int dir  = grp;

  const float* Wih = dir ? Wih_b : Wih_f;
  const float* Whh = dir ? Whh_b : Whh_f;
  const float* bih = dir ? bih_b : bih_f;
  const float* bhh = dir ? bhh_b : bhh_f;

  const int lane = tid & 63;
  const int lwv  = (tid >> 6) & 3;  // wave slice within group: 0..3
  const int col  = lane & 15;
  const int quad = lane >> 4;
  const int j0   = lwv * 32 + col;  // unit for col-tile 0
  const int j1   = j0 + 16;         // unit for col-tile 1

  __shared__ __align__(16) _Float16 xA[2][CHUNK][XA_LD];
  __shared__ __align__(16) _Float16 xPL[2][CHUNK][XP_LD];
  __shared__ __align__(16) _Float16 hist[2][CHUNK + 1][HI_LD];

  const float LOG2E = 1.44269504f;

  // ---- stationary weight fragments [ct][g][kt], pre-scaled for exp2 gates ----
  half8 whf[2][3][4];   // 96 VGPR
  half8 wif[2][3][4];   // 96 VGPR
#pragma unroll
  for (int ct = 0; ct < 2; ++ct) {
    const int jct = lwv * 32 + ct * 16 + col;
#pragma unroll
    for (int g = 0; g < 3; ++g) {
      const float gs = (g == 2) ? 2.0f * LOG2E : LOG2E;
#pragma unroll
      for (int kt = 0; kt < 4; ++kt) {
        const float* sh = Whh + (size_t)(g * H_DIM + jct) * H_DIM + kt * 32 + quad * 8;
        const float* si = Wih + (size_t)(g * H_DIM + jct) * DX + kt * 32 + quad * 8;
        half8 vh, vi;
#pragma unroll
        for (int e = 0; e < 8; ++e) {
          vh[e] = (_Float16)(sh[e] * gs);
          vi[e] = (_Float16)(si[e] * gs);
        }
        whf[ct][g][kt] = vh;
        wif[ct][g][kt] = vi;
      }
    }
  }
  float br[2], bz[2], bn[2];
  floatx4 cNbv[2];
#pragma unroll
  for (int ct = 0; ct < 2; ++ct) {
    const int jct = lwv * 32 + ct * 16 + col;
    br[ct] = (bih[jct] + bhh[jct]) * LOG2E;
    bz[ct] = (bih[H_DIM + jct] + bhh[H_DIM + jct]) * LOG2E;
    bn[ct] = bih[2 * H_DIM + jct] * (2.0f * LOG2E);
    float bh = bhh[2 * H_DIM + jct] * (2.0f * LOG2E);
    cNbv[ct] = (floatx4){bh, bh, bh, bh};
  }

  // ---- Wfc fragments for fused FC (lwv 0..1 of each group) ----
  half8 fcf[4];
  if (lwv < 2) {
#pragma unroll
    for (int kt = 0; kt < 4; ++kt) {
      half8 v;
#pragma unroll
      for (int e = 0; e < 8; ++e) {
        int k = kt * 32 + quad * 8 + e;
        v[e] = (col < K_CLS) ? (_Float16)Wfc[(size_t)col * (2 * H_DIM) + dir * H_DIM + k]
                             : (_Float16)0.f;
      }
      fcf[kt] = v;
    }
  }

  if (ltid < H_DIM) hist[grp][0][ltid] = (_Float16)0.f;

  // ---- x prefetch: thread covers row s_row of its group's chunk, 16 floats ----
  const int s_row = ltid >> 3;        // 0..31
  const int cb    = (ltid & 7) * 16;  // 0..112
  float4 px0, px1, px2, px3;
  {
    int t0 = dir ? (T_LEN - 1 - s_row) : s_row;
    const float* xr = x + ((size_t)b * T_LEN + t0) * DX + cb;
    px0 = *(const float4*)xr;        px1 = *(const float4*)(xr + 4);
    px2 = *(const float4*)(xr + 8);  px3 = *(const float4*)(xr + 12);
  }

  float hold0 = 0.f, hold1 = 0.f;
  const floatx4 z4 = {0.f, 0.f, 0.f, 0.f};
  __syncthreads();

  for (int c = 0; c < NCHUNKS; ++c) {
    // ---- stage x chunk into LDS (f16) ----
    {
      half8 lo, hi;
      lo[0] = (_Float16)px0.x; lo[1] = (_Float16)px0.y; lo[2] = (_Float16)px0.z; lo[3] = (_Float16)px0.w;
      lo[4] = (_Float16)px1.x; lo[5] = (_Float16)px1.y; lo[6] = (_Float16)px1.z; lo[7] = (_Float16)px1.w;
      hi[0] = (_Float16)px2.x; hi[1] = (_Float16)px2.y; hi[2] = (_Float16)px2.z; hi[3] = (_Float16)px2.w;
      hi[4] = (_Float16)px3.x; hi[5] = (_Float16)px3.y; hi[6] = (_Float16)px3.z; hi[7] = (_Float16)px3.w;
      *(half8*)&xA[grp][s_row][cb] = lo;
      *(half8*)&xA[grp][s_row][cb + 8] = hi;
    }
    LGKM_BARRIER();

    // ---- xp = (x @ Wih^T + bias), pre-scaled, packed [row][j*4] ----
#pragma unroll
    for (int mt = 0; mt < 2; ++mt) {
      half8 af[4];
#pragma unroll
      for (int kt = 0; kt < 4; ++kt)
        af[kt] = *(const half8*)&xA[grp][mt * 16 + col][kt * 32 + quad * 8];
#pragma unroll
      for (int ct = 0; ct < 2; ++ct) {
        floatx4 pr = z4, pz = z4, pn = z4;
#pragma unroll
        for (int kt = 0; kt < 4; ++kt) {
          pr = __builtin_amdgcn_mfma_f32_16x16x32_f16(af[kt], wif[ct][0][kt], pr, 0, 0, 0);
          pz = __builtin_amdgcn_mfma_f32_16x16x32_f16(af[kt], wif[ct][1][kt], pz, 0, 0, 0);
          pn = __builtin_amdgcn_mfma_f32_16x16x32_f16(af[kt], wif[ct][2][kt], pn, 0, 0, 0);
        }
        const int jw = (ct ? j1 : j0) * 4;
#pragma unroll
        for (int i = 0; i < 4; ++i) {
          half4 w;
          w[0] = (_Float16)(pr[i] + br[ct]);
          w[1] = (_Float16)(pz[i] + bz[ct]);
          w[2] = (_Float16)(pn[i] + bn[ct]);
          w[3] = (_Float16)0.f;
          *(half4*)&xPL[grp][mt * 16 + quad * 4 + i][jw] = w;
        }
      }
    }

    // prefetch next chunk's x (stays in flight across the scan)
    if (c + 1 < NCHUNKS) {
      int s  = (c + 1) * CHUNK + s_row;
      int t0 = dir ? (T_LEN - 1 - s) : s;
      const float* xr = x + ((size_t)b * T_LEN + t0) * DX + cb;
      px0 = *(const float4*)xr;        px1 = *(const float4*)(xr + 4);
      px2 = *(const float4*)(xr + 8);  px3 = *(const float4*)(xr + 12);
    }
    LGKM_BARRIER();

    uint2 xv0 = *(const uint2*)&xPL[grp][0][j0 * 4];
    uint2 xv1 = *(const uint2*)&xPL[grp][0][j1 * 4];

    // ---- sequential scan (fully unrolled: immediate LDS offsets) ----
#pragma unroll
    for (int s = 0; s < CHUNK; ++s) {
      // broadcast h fragments: address depends only on quad -> every A-row = h
      half8 haf[4];
#pragma unroll
      for (int kt = 0; kt < 4; ++kt)
        haf[kt] = *(const half8*)&hist[grp][s][kt * 32 + quad * 8];
      uint2 xvn0 = *(const uint2*)&xPL[grp][(s + 1) & (CHUNK - 1)][j0 * 4];
      uint2 xvn1 = *(const uint2*)&xPL[grp][(s + 1) & (CHUNK - 1)][j1 * 4];

      half2v xa0 = __builtin_bit_cast(half2v, xv0.x);
      half2v xb0 = __builtin_bit_cast(half2v, xv0.y);
      half2v xa1 = __builtin_bit_cast(half2v, xv1.x);
      half2v xb1 = __builtin_bit_cast(half2v, xv1.y);
      float xr0 = (float)xa0.x, xz0 = (float)xa0.y, xn0 = (float)xb0.x;
      float xr1 = (float)xa1.x, xz1 = (float)xa1.y, xn1 = (float)xb1.x;
      floatx4 cR0 = {xr0, xr0, xr0, xr0}, cZ0 = {xz0, xz0, xz0, xz0};
      floatx4 cR1 = {xr1, xr1, xr1, xr1}, cZ1 = {xz1, xz1, xz1, xz1};

      // 24 independent MFMAs; per-step scalars ride in as C operands
      floatx4 a0[3][4], a1[3][4];
#pragma unroll
      for (int g = 0; g < 3; ++g) {
#pragma unroll
        for (int kt = 0; kt < 4; ++kt) {
          floatx4 c0 = (kt == 0) ? ((g == 0) ? cR0 : (g == 1) ? cZ0 : cNbv[0]) : z4;
          a0[g][kt] = __builtin_amdgcn_mfma_f32_16x16x32_f16(haf[kt], whf[0][g][kt], c0, 0, 0, 0);
        }
      }
#pragma unroll
      for (int g = 0; g < 3; ++g) {
#pragma unroll
        for (int kt = 0; kt < 4; ++kt) {
          floatx4 c1 = (kt == 0) ? ((g == 0) ? cR1 : (g == 1) ? cZ1 : cNbv[1]) : z4;
          a1[g][kt] = __builtin_amdgcn_mfma_f32_16x16x32_f16(haf[kt], whf[1][g][kt], c1, 0, 0, 0);
        }
      }

      // gates for col-tile 0 (valid in every lane: all A-rows identical)
      {
        float ar = (a0[0][0][0] + a0[0][1][0]) + (a0[0][2][0] + a0[0][3][0]);
        float rr = __builtin_amdgcn_rcpf(1.f + __builtin_amdgcn_exp2f(-ar));
        float az = (a0[1][0][0] + a0[1][1][0]) + (a0[1][2][0] + a0[1][3][0]);
        float zz = __builtin_amdgcn_rcpf(1.f + __builtin_amdgcn_exp2f(-az));
        float an = (a0[2][0][0] + a0[2][1][0]) + (a0[2][2][0] + a0[2][3][0]);
        float yn = fmaf(rr, an, xn0);
        float t  = __builtin_amdgcn_exp2f(-yn);
        float nn = fmaf(2.f, __builtin_amdgcn_rcpf(1.f + t), -1.f);
        hold0 = fmaf(zz, hold0 - nn, nn);
      }
      // gates for col-tile 1
      {
        float ar = (a1[0][0][0] + a1[0][1][0]) + (a1[0][2][0] + a1[0][3][0]);
        float rr = __builtin_amdgcn_rcpf(1.f + __builtin_amdgcn_exp2f(-ar));
        float az = (a1[1][0][0] + a1[1][1][0]) + (a1[1][2][0] + a1[1][3][0]);
        float zz = __builtin_amdgcn_rcpf(1.f + __builtin_amdgcn_exp2f(-az));
        float an = (a1[2][0][0] + a1[2][1][0]) + (a1[2][2][0] + a1[2][3][0]);
        float yn = fmaf(rr, an, xn1);
        float t  = __builtin_amdgcn_exp2f(-yn);
        float nn = fmaf(2.f, __builtin_amdgcn_rcpf(1.f + t), -1.f);
        hold1 = fmaf(zz, hold1 - nn, nn);
      }

      if (quad == 0) {
        hist[grp][s + 1][j0] = (_Float16)hold0;
        hist[grp][s + 1][j1] = (_Float16)hold1;
      }
      LGKM_BARRIER();
      xv0 = xvn0;
      xv1 = xvn1;
    }

    // ---- fused FC for this chunk (lwv 0..1); lwv 2 carries h ----
    if (lwv < 2) {
      floatx4 fa = z4;
#pragma unroll
      for (int kt = 0; kt < 4; ++kt) {
        half8 af = *(const half8*)&hist[grp][1 + lwv * 16 + col][kt * 32 + quad * 8];
        fa = __builtin_amdgcn_mfma_f32_16x16x32_f16(af, fcf[kt], fa, 0, 0, 0);
      }
      if (col < K_CLS) {
#pragma unroll
        for (int i = 0; i < 4; ++i) {
          int t  = c * CHUNK + lwv * 16 + quad * 4 + i;
          int tt = dir ? (T_LEN - 1 - t) : t;
          atomicAdd(out + ((size_t)b * T_LEN + tt) * K_CLS + col, fa[i]);
        }
      }
    } else if (lwv == 2) {
      // carry h into row 0 for the next chunk (ordered by next chunk's barriers)
      ((unsigned int*)&hist[grp][0][0])[lane] = ((const unsigned int*)&hist[grp][CHUNK][0])[lane];
    }
  }
}

extern "C" void kernel_launch(void* const* d_in, const int* in_sizes, int n_in,
                              void* d_out, int out_size, void* d_ws, size_t ws_size,
                              hipStream_t stream) {
  (void)in_sizes; (void)n_in; (void)d_ws; (void)ws_size; (void)out_size;
  const float* x     = (const float*)d_in[0];
  const float* Wih_f = (const float*)d_in[1];
  const float* Whh_f = (const float*)d_in[2];
  const float* bih_f = (const float*)d_in[3];
  const float* bhh_f = (const float*)d_in[4];
  const float* Wih_b = (const float*)d_in[5];
  const float* Whh_b = (const float*)d_in[6];
  const float* bih_b = (const float*)d_in[7];
  const float* bhh_b = (const float*)d_in[8];
  const float* Wfc   = (const float*)d_in[9];
  const float* bfc   = (const float*)d_in[10];
  float* out = (float*)d_out;

  const int n_out = B_SZ * T_LEN * K_CLS;
  init_out_kernel<<<(n_out + 255) / 256, 256, 0, stream>>>(out, bfc);
  gru_bidir_kernel<<<B_SZ, 512, 0, stream>>>(x, Wih_f, Whh_f, bih_f, bhh_f,
                                             Wih_b, Whh_b, bih_b, bhh_b, Wfc, out);
}

// Round 10
// 1721.165 us; speedup vs baseline: 2.1807x; 2.1807x over previous
//
#include <hip/hip_runtime.h>
#include <cstdint>
#include <cstddef>

#define T_LEN   4096
#define B_SZ    32
#define H_DIM   128
#define DX      128
#define K_CLS   10
#define CHUNK   32
#define NCHUNKS (T_LEN / CHUNK)
#define XA_LD   136   // f16 per xA row
#define XP_LD   520   // f16 per xPL row: 128 units * 4 (r,z,n,pad) + 8 pad
#define HI_LD   136

typedef _Float16 half2v  __attribute__((ext_vector_type(2)));
typedef _Float16 half4   __attribute__((ext_vector_type(4)));
typedef _Float16 half8   __attribute__((ext_vector_type(8)));
typedef float    floatx4 __attribute__((ext_vector_type(4)));

// Raw barrier: orders LDS ops only (no vmcnt drain).
#define LGKM_BARRIER() do {                                   \
    asm volatile("s_waitcnt lgkmcnt(0)" ::: "memory");        \
    __builtin_amdgcn_s_barrier();                             \
    asm volatile("" ::: "memory");                            \
  } while (0)

__global__ void __launch_bounds__(256) init_out_kernel(float* __restrict__ out,
                                                       const float* __restrict__ bfc) {
  int i = blockIdx.x * 256 + threadIdx.x;
  if (i < B_SZ * T_LEN * K_CLS) out[i] = bfc[i % K_CLS];
}

// One block per (batch, direction) scan. 8 waves (512 threads, 2/SIMD).
// BEST-KNOWN CONFIG (R2, 1662 us): structural ledger of refuted alternatives —
//  - chain micro-trims (C-folding/full-unroll/no exec-mask): flat (R3)
//  - 4 waves x 24 MFMA (1/SIMD): -17% (R4) — wave interleave matters
//  - DPP h-broadcast replacing 3 of 4 ds_reads: -15% (R5) — cross-lane ops
//    land on the serial critical path
//  - fusing both directions into one block (needs ~240 VGPR): blocked, the
//    toolchain caps 512-thread MFMA kernels at 128 VGPR regardless of
//    __launch_bounds__ 2nd arg or amdgpu_waves_per_eu (R6-R9, 4 attempts)
// Remaining stall is the ~975cy/step barrier-round (barrier + LDS round-trip
// + MFMA latency + serial transcendental chain), with both waves per SIMD
// lockstepped on the same scan. Latency-bound, not a mem/compute roofline.
//  - hp = Whh @ h via MFMA, all A-rows = broadcast h; each wave owns 16 units
//  - Whh/Wih stationary in VGPRs, pre-scaled by log2e (r,z) / 2log2e (n)
//  - xp packed [s][j*4+g], one b64 read/step, prefetched one step ahead
//  - raw lgkm-only barriers in the scan (no vmcnt drains on the critical path)
__global__ void __launch_bounds__(512, 2)
gru_bidir_kernel(const float* __restrict__ x,
                 const float* __restrict__ Wih_f, const float* __restrict__ Whh_f,
                 const float* __restrict__ bih_f, const float* __restrict__ bhh_f,
                 const float* __restrict__ Wih_b, const float* __restrict__ Whh_b,
                 const float* __restrict__ bih_b, const float* __restrict__ bhh_b,
                 const float* __restrict__ Wfc, float* __restrict__ out) {
  const int tid = threadIdx.x;
  const int bid = blockIdx.x;
  const int b   = bid & (B_SZ - 1);
  const int dir = bid >> 5;

  const float* Wih = dir ? Wih_b : Wih_f;
  const float* Whh = dir ? Whh_b : Whh_f;
  const float* bih = dir ? bih_b : bih_f;
  const float* bhh = dir ? bhh_b : bhh_f;

  const int lane = tid & 63;
  const int wv   = tid >> 6;      // 0..7
  const int col  = lane & 15;
  const int quad = lane >> 4;
  const int jloc = wv * 16 + col; // this lane's hidden unit

  __shared__ __align__(16) _Float16 xA[CHUNK][XA_LD];
  __shared__ __align__(16) _Float16 xPL[CHUNK][XP_LD];
  __shared__ __align__(16) _Float16 hist[CHUNK + 1][HI_LD];

  const float LOG2E = 1.44269504f;

  // ---- stationary weight fragments, pre-scaled for exp2-native gates ----
  half8 whf[3][4];
  half8 wif[3][4];
#pragma unroll
  for (int g = 0; g < 3; ++g) {
    const float gs = (g == 2) ? 2.0f * LOG2E : LOG2E;
#pragma unroll
    for (int kt = 0; kt < 4; ++kt) {
      const float* sh = Whh + (size_t)(g * H_DIM + jloc) * H_DIM + kt * 32 + quad * 8;
      const float* si = Wih + (size_t)(g * H_DIM + jloc) * DX + kt * 32 + quad * 8;
      half8 vh, vi;
#pragma unroll
      for (int e = 0; e < 8; ++e) {
        vh[e] = (_Float16)(sh[e] * gs);
        vi[e] = (_Float16)(si[e] * gs);
      }
      whf[g][kt] = vh;
      wif[g][kt] = vi;
    }
  }
  const float bias_r = (bih[jloc] + bhh[jloc]) * LOG2E;
  const float bias_z = (bih[H_DIM + jloc] + bhh[H_DIM + jloc]) * LOG2E;
  const float bias_n = bih[2 * H_DIM + jloc] * (2.0f * LOG2E);
  const float bhn_s  = bhh[2 * H_DIM + jloc] * (2.0f * LOG2E);

  // ---- Wfc fragments for fused FC (waves 0..1) ----
  half8 fcf[4];
  if (wv < 2) {
#pragma unroll
    for (int kt = 0; kt < 4; ++kt) {
      half8 v;
#pragma unroll
      for (int e = 0; e < 8; ++e) {
        int k = kt * 32 + quad * 8 + e;
        v[e] = (col < K_CLS) ? (_Float16)Wfc[(size_t)col * (2 * H_DIM) + dir * H_DIM + k]
                             : (_Float16)0.f;
      }
      fcf[kt] = v;
    }
  }

  // A-operand fragments: only col==0 lanes ever load (A row 0 = h); rest are 0.
  half8 hz;
#pragma unroll
  for (int e = 0; e < 8; ++e) hz[e] = (_Float16)0.f;
  half8 haf0 = hz, haf1 = hz, haf2 = hz, haf3 = hz;

  if (tid < H_DIM) hist[0][tid] = (_Float16)0.f;

  // ---- x prefetch: thread covers row s_row, 8 consecutive floats ----
  const int s_row = tid >> 4;
  const int cb    = (tid & 15) * 8;
  float4 px0, px1;
  {
    int t0 = dir ? (T_LEN - 1 - s_row) : s_row;
    const float* xr = x + ((size_t)b * T_LEN + t0) * DX + cb;
    px0 = *(const float4*)xr;
    px1 = *(const float4*)(xr + 4);
  }

  float hold = 0.f;  // carried h for unit jloc
  const floatx4 z4 = {0.f, 0.f, 0.f, 0.f};
  __syncthreads();

  for (int c = 0; c < NCHUNKS; ++c) {
    // ---- stage x chunk into LDS (f16) ----
    {
      half8 v;
      v[0] = (_Float16)px0.x; v[1] = (_Float16)px0.y; v[2] = (_Float16)px0.z; v[3] = (_Float16)px0.w;
      v[4] = (_Float16)px1.x; v[5] = (_Float16)px1.y; v[6] = (_Float16)px1.z; v[7] = (_Float16)px1.w;
      *(half8*)&xA[s_row][cb] = v;
    }
    LGKM_BARRIER();

    // ---- xp = (x @ Wih^T + bias), pre-scaled, packed [row][j*4+g] ----
#pragma unroll
    for (int mt = 0; mt < 2; ++mt) {
      half8 af[4];
#pragma unroll
      for (int kt = 0; kt < 4; ++kt)
        af[kt] = *(const half8*)&xA[mt * 16 + col][kt * 32 + quad * 8];
      floatx4 pr = z4, pz = z4, pn = z4;
#pragma unroll
      for (int kt = 0; kt < 4; ++kt) {
        pr = __builtin_amdgcn_mfma_f32_16x16x32_f16(af[kt], wif[0][kt], pr, 0, 0, 0);
        pz = __builtin_amdgcn_mfma_f32_16x16x32_f16(af[kt], wif[1][kt], pz, 0, 0, 0);
        pn = __builtin_amdgcn_mfma_f32_16x16x32_f16(af[kt], wif[2][kt], pn, 0, 0, 0);
      }
#pragma unroll
      for (int i = 0; i < 4; ++i) {
        half4 w;
        w[0] = (_Float16)(pr[i] + bias_r);
        w[1] = (_Float16)(pz[i] + bias_z);
        w[2] = (_Float16)(pn[i] + bias_n);
        w[3] = (_Float16)0.f;
        *(half4*)&xPL[mt * 16 + quad * 4 + i][jloc * 4] = w;
      }
    }

    // prefetch next chunk's x (stays in flight across the scan)
    if (c + 1 < NCHUNKS) {
      int s  = (c + 1) * CHUNK + s_row;
      int t0 = dir ? (T_LEN - 1 - s) : s;
      const float* xr = x + ((size_t)b * T_LEN + t0) * DX + cb;
      px0 = *(const float4*)xr;
      px1 = *(const float4*)(xr + 4);
    }
    LGKM_BARRIER();

    uint2 xv = *(const uint2*)&xPL[0][jloc * 4];

    // ---- sequential scan ----
#pragma unroll 2
    for (int s = 0; s < CHUNK; ++s) {
      if (col == 0) {
        haf0 = *(const half8*)&hist[s][quad * 8];
        haf1 = *(const half8*)&hist[s][32 + quad * 8];
        haf2 = *(const half8*)&hist[s][64 + quad * 8];
        haf3 = *(const half8*)&hist[s][96 + quad * 8];
      }
      uint2 xvn = *(const uint2*)&xPL[(s + 1) & (CHUNK - 1)][jloc * 4];

      // 12 independent depth-1 MFMAs (r first so sigmoid(r) can start early)
      floatx4 cr0 = __builtin_amdgcn_mfma_f32_16x16x32_f16(haf0, whf[0][0], z4, 0, 0, 0);
      floatx4 cr1 = __builtin_amdgcn_mfma_f32_16x16x32_f16(haf1, whf[0][1], z4, 0, 0, 0);
      floatx4 cr2 = __builtin_amdgcn_mfma_f32_16x16x32_f16(haf2, whf[0][2], z4, 0, 0, 0);
      floatx4 cr3 = __builtin_amdgcn_mfma_f32_16x16x32_f16(haf3, whf[0][3], z4, 0, 0, 0);
      floatx4 cz0 = __builtin_amdgcn_mfma_f32_16x16x32_f16(haf0, whf[1][0], z4, 0, 0, 0);
      floatx4 cz1 = __builtin_amdgcn_mfma_f32_16x16x32_f16(haf1, whf[1][1], z4, 0, 0, 0);
      floatx4 cz2 = __builtin_amdgcn_mfma_f32_16x16x32_f16(haf2, whf[1][2], z4, 0, 0, 0);
      floatx4 cz3 = __builtin_amdgcn_mfma_f32_16x16x32_f16(haf3, whf[1][3], z4, 0, 0, 0);
      floatx4 cn0 = __builtin_amdgcn_mfma_f32_16x16x32_f16(haf0, whf[2][0], z4, 0, 0, 0);
      floatx4 cn1 = __builtin_amdgcn_mfma_f32_16x16x32_f16(haf1, whf[2][1], z4, 0, 0, 0);
      floatx4 cn2 = __builtin_amdgcn_mfma_f32_16x16x32_f16(haf2, whf[2][2], z4, 0, 0, 0);
      floatx4 cn3 = __builtin_amdgcn_mfma_f32_16x16x32_f16(haf3, whf[2][3], z4, 0, 0, 0);

      float ar = (cr0[0] + cr1[0]) + (cr2[0] + cr3[0]);  // valid in quad==0
      float az = (cz0[0] + cz1[0]) + (cz2[0] + cz3[0]);
      float an = (cn0[0] + cn1[0]) + (cn2[0] + cn3[0]);

      half2v x01 = __builtin_bit_cast(half2v, xv.x);  // xr, xz (log2e-scaled)
      half2v x23 = __builtin_bit_cast(half2v, xv.y);  // xn (2log2e-scaled)

      // sigmoid(x) = rcp(1 + 2^-y), y pre-scaled; saturates correctly w/o clamps
      float rr = __builtin_amdgcn_rcpf(1.f + __builtin_amdgcn_exp2f(-((float)x01.x + ar)));
      float zz = __builtin_amdgcn_rcpf(1.f + __builtin_amdgcn_exp2f(-((float)x01.y + az)));
      float yn = fmaf(rr, an + bhn_s, (float)x23.x);
      // tanh: fma(2, rcp(1+2^-2y), -1) — saturates correctly, NaN-free, no clamp
      float t  = __builtin_amdgcn_exp2f(-yn);
      float nn = fmaf(2.f, __builtin_amdgcn_rcpf(1.f + t), -1.f);
      hold = fmaf(zz, hold - nn, nn);

      if (quad == 0) hist[s + 1][jloc] = (_Float16)hold;
      LGKM_BARRIER();
      xv = xvn;
    }

    // ---- fused FC for this chunk (waves 0..1) ----
    if (wv < 2) {
      floatx4 fa = z4;
#pragma unroll
      for (int kt = 0; kt < 4; ++kt) {
        half8 af = *(const half8*)&hist[1 + wv * 16 + col][kt * 32 + quad * 8];
        fa = __builtin_amdgcn_mfma_f32_16x16x32_f16(af, fcf[kt], fa, 0, 0, 0);
      }
      if (col < K_CLS) {
#pragma unroll
        for (int i = 0; i < 4; ++i) {
          int t  = c * CHUNK + wv * 16 + quad * 4 + i;
          int tt = dir ? (T_LEN - 1 - t) : t;
          atomicAdd(out + ((size_t)b * T_LEN + tt) * K_CLS + col, fa[i]);
        }
      }
    }
    // carry h into row 0 for the next chunk (ordered by next chunk's barriers)
    if (tid >= 256 && tid < 256 + H_DIM) hist[0][tid - 256] = hist[CHUNK][tid - 256];
  }
}

extern "C" void kernel_launch(void* const* d_in, const int* in_sizes, int n_in,
                              void* d_out, int out_size, void* d_ws, size_t ws_size,
                              hipStream_t stream) {
  (void)in_sizes; (void)n_in; (void)d_ws; (void)ws_size; (void)out_size;
  const float* x     = (const float*)d_in[0];
  const float* Wih_f = (const float*)d_in[1];
  const float* Whh_f = (const float*)d_in[2];
  const float* bih_f = (const float*)d_in[3];
  const float* bhh_f = (const float*)d_in[4];
  const float* Wih_b = (const float*)d_in[5];
  const float* Whh_b = (const float*)d_in[6];
  const float* bih_b = (const float*)d_in[7];
  const float* bhh_b = (const float*)d_in[8];
  const float* Wfc   = (const float*)d_in[9];
  const float* bfc   = (const float*)d_in[10];
  float* out = (float*)d_out;

  const int n_out = B_SZ * T_LEN * K_CLS;
  init_out_kernel<<<(n_out + 255) / 256, 256, 0, stream>>>(out, bfc);
  gru_bidir_kernel<<<B_SZ * 2, 512, 0, stream>>>(x, Wih_f, Whh_f, bih_f, bhh_f,
                                                 Wih_b, Whh_b, bih_b, bhh_b, Wfc, out);
}